// Round 15
// baseline (162.458 us; speedup 1.0000x reference)
//
#include <hip/hip_runtime.h>
#include <hip/hip_bf16.h>

#define V_ 32000
#define E_ 100
#define H_ 128
#define B_ 1024
#define T_ 256

typedef float f32x4 __attribute__((ext_vector_type(4)));
typedef int   i32x4 __attribute__((ext_vector_type(4)));
typedef __bf16 bf16x8 __attribute__((ext_vector_type(8)));
typedef __bf16 bf16x4 __attribute__((ext_vector_type(4)));

__device__ __forceinline__ f32x4 mfma16(bf16x8 a, bf16x8 b, f32x4 c) {
    return __builtin_amdgcn_mfma_f32_16x16x32_bf16(a, b, c, 0, 0, 0);
}

// ---------------------------------------------------------------------------
// K0: pp[v][h] = bf16( emb[v,:] @ W_ih^T + b_ih + b_hh )  (K = 100, f32 acc)
// Input projection depends only on vocab id -> precompute once for all ids.
// grid 500 x 512thr; block covers 64 vocab; 8 waves = 4 v-tiles x 2 h-halves.
// ---------------------------------------------------------------------------
__global__ __launch_bounds__(512, 1) void k0_pp(
    const float* __restrict__ emb, const float* __restrict__ Wih,
    const float* __restrict__ bih, const float* __restrict__ bhh,
    __bf16* __restrict__ pp)
{
    const int tid = threadIdx.x;
    const int lane = tid & 63, w = tid >> 6;
    const int nt = w >> 1;               // vocab tile 0..3
    const int mh = w & 1;                // h half 0..1 (4 m-tiles each)
    const int v0 = blockIdx.x * 64;
    const int sub = lane >> 4, rc = lane & 15;
    const f32x4 z = {0.f, 0.f, 0.f, 0.f};

    bf16x8 af[4][4];
#pragma unroll
    for (int m = 0; m < 4; ++m)
#pragma unroll
        for (int kc = 0; kc < 4; ++kc) {
            int row = (mh * 4 + m) * 16 + rc;
            int k0 = kc * 32 + sub * 8;
            const float* s = Wih + (size_t)row * E_ + k0;
            f32x4 p0 = (k0 + 4 <= E_) ? *(const f32x4*)s : z;
            f32x4 p1 = (k0 + 8 <= E_) ? *(const f32x4*)(s + 4) : z;
            bf16x8 h8;
#pragma unroll
            for (int e = 0; e < 4; ++e) {
                h8[e] = (__bf16)p0[e];
                h8[4 + e] = (__bf16)p1[e];
            }
            af[m][kc] = h8;
        }

    bf16x8 bf[4];
#pragma unroll
    for (int kc = 0; kc < 4; ++kc) {
        int vrow = v0 + nt * 16 + rc;
        int k0 = kc * 32 + sub * 8;
        const float* s = emb + (size_t)vrow * E_ + k0;
        f32x4 p0 = (k0 + 4 <= E_) ? *(const f32x4*)s : z;
        f32x4 p1 = (k0 + 8 <= E_) ? *(const f32x4*)(s + 4) : z;
        bf16x8 h8;
#pragma unroll
        for (int e = 0; e < 4; ++e) {
            h8[e] = (__bf16)p0[e];
            h8[4 + e] = (__bf16)p1[e];
        }
        bf[kc] = h8;
    }

    f32x4 acc[4];
#pragma unroll
    for (int m = 0; m < 4; ++m) {
        int h0 = (mh * 4 + m) * 16 + sub * 4;
        acc[m] = *(const f32x4*)&bih[h0] + *(const f32x4*)&bhh[h0];
    }
#pragma unroll
    for (int kc = 0; kc < 4; ++kc)
#pragma unroll
        for (int m = 0; m < 4; ++m)
            acc[m] = mfma16(af[m][kc], bf[kc], acc[m]);

#pragma unroll
    for (int m = 0; m < 4; ++m) {
        int v = v0 + nt * 16 + rc;
        int h0 = (mh * 4 + m) * 16 + sub * 4;
        bf16x4 o;
#pragma unroll
        for (int r = 0; r < 4; ++r) o[r] = (__bf16)acc[m][r];
        *(bf16x4*)&pp[(size_t)v * H_ + h0] = o;
    }
}

// ---------------------------------------------------------------------------
// K2: RNN scan (R10 structure, measured 94.7 µs — fused staggered gathers).
// 64 blocks x 16 batch; 8 waves (2/SIMD); wave w owns hidden rows
// [16w,16w+16). xt from pp[x[b,t]] gathers, STAGGERED one-per-step (issued
// in step t for step t+4; sched_barrier(0) pins them per-step). Indices
// i32x4 loaded in step 3 of each group, pointer clamped at tail.
// Position-named regs (counted vmcnt). Static LDS ping-pong; xt folded into
// MFMA C-init; 1 barrier/step.
// ---------------------------------------------------------------------------
__global__ __launch_bounds__(512, 1) void k2_rnn(
    const int* __restrict__ x, const __bf16* __restrict__ pp,
    const float* __restrict__ Whh, __bf16* __restrict__ hg)
{
    __shared__ __align__(16) __bf16 Hg[2][2048];
    const int tid = threadIdx.x;
    const int lane = tid & 63, w = tid >> 6;
    const int bi = blockIdx.x;
    const int b0 = bi * 16;
    const int sub = lane >> 4, c = lane & 15;

    // A fragments: W_hh rows w*16 + c (bf16); loop-invariant
    bf16x8 wah[4];
#pragma unroll
    for (int kc = 0; kc < 4; ++kc) {
        const float* src = Whh + (size_t)(w * 16 + c) * H_ + kc * 32 + sub * 8;
        f32x4 p0 = *(const f32x4*)src, p1 = *(const f32x4*)(src + 4);
        bf16x8 h8;
#pragma unroll
        for (int e = 0; e < 4; ++e) {
            h8[e] = (__bf16)p0[e];
            h8[4 + e] = (__bf16)p1[e];
        }
        wah[kc] = h8;
    }

    if (tid < 256) {
        bf16x8 z8;
#pragma unroll
        for (int e = 0; e < 8; ++e) z8[e] = (__bf16)0.0f;
        *(bf16x8*)&Hg[0][tid * 8] = z8;
    }
    __syncthreads();

    const int i0 = w * 16 + sub * 4;            // this lane's 4 hidden-out rows
    const int* xrow = x + (size_t)(b0 + c) * T_; // this lane's batch index row
    const __bf16* ppi = pp + i0;

    // LDS write elem-offset for hidden rows i0..i0+3, col c (granule layout)
    const int wb = (((w >> 1) * 64 + ((w & 1) * 2 + (sub >> 1)) * 16 + c) << 3)
                 + (sub & 1) * 4;

    bf16x4 h4;                                   // last-written h (for hg)

    // GBODY: one gather / index-load, placed after MFMA issue within the step
#define K2_STEP(PK, XREG, GBODY) do {                                       \
        const __bf16* Hp = &Hg[PK][0];                                      \
        bf16x8 hb0 = *(const bf16x8*)(Hp + lane * 8);                       \
        bf16x8 hb1 = *(const bf16x8*)(Hp + 512 + lane * 8);                 \
        bf16x8 hb2 = *(const bf16x8*)(Hp + 1024 + lane * 8);                \
        bf16x8 hb3 = *(const bf16x8*)(Hp + 1536 + lane * 8);                \
        f32x4 xf;                                                           \
        _Pragma("unroll")                                                   \
        for (int r = 0; r < 4; ++r) xf[r] = (float)XREG[r];                 \
        f32x4 zz = {0.f, 0.f, 0.f, 0.f};                                    \
        f32x4 a0 = mfma16(wah[0], hb0, xf);                                 \
        f32x4 a1 = mfma16(wah[1], hb1, zz);                                 \
        a0 = mfma16(wah[2], hb2, a0);                                       \
        a1 = mfma16(wah[3], hb3, a1);                                       \
        GBODY;                                                              \
        f32x4 s = a0 + a1;                                                  \
        _Pragma("unroll")                                                   \
        for (int r = 0; r < 4; ++r) {                                       \
            float e;                                                        \
            asm("v_exp_f32 %0, %1" : "=v"(e) : "v"(s[r] * 2.8853900817779268f)); \
            float ep1 = e + 1.0f;                                           \
            float rcp;                                                      \
            asm("v_rcp_f32 %0, %1" : "=v"(rcp) : "v"(ep1));                 \
            h4[r] = (__bf16)(1.0f - 2.0f * rcp);                            \
        }                                                                   \
        *(bf16x4*)&Hg[(PK) ^ 1][wb] = h4;                                   \
        asm volatile("s_waitcnt lgkmcnt(0)" ::: "memory");                  \
        __builtin_amdgcn_s_barrier();                                       \
        __builtin_amdgcn_sched_barrier(0);                                  \
    } while (0)

    // prologue: indices + gathers for steps 0..3; indices for steps 4..7
    i32x4 xs0 = *(const i32x4*)(xrow);
    bf16x4 xc0 = *(const bf16x4*)(ppi + (size_t)xs0[0] * H_);
    bf16x4 xc1 = *(const bf16x4*)(ppi + (size_t)xs0[1] * H_);
    bf16x4 xc2 = *(const bf16x4*)(ppi + (size_t)xs0[2] * H_);
    bf16x4 xc3 = *(const bf16x4*)(ppi + (size_t)xs0[3] * H_);
    i32x4 xsA = *(const i32x4*)(xrow + 4);

    for (int j = 0; j < T_ / 4; ++j) {
        bf16x4 xn0, xn1, xn2, xn3;
        i32x4 xsB;
        // clamped pointers: tail groups read valid (unused) data
        int tg = 4 * (j + 2);
        const int* xnext = xrow + (tg <= T_ - 4 ? tg : T_ - 4);

        K2_STEP(0, xc0, { xn0 = *(const bf16x4*)(ppi + (size_t)xsA[0] * H_); });
        K2_STEP(1, xc1, { xn1 = *(const bf16x4*)(ppi + (size_t)xsA[1] * H_); });
        K2_STEP(0, xc2, { xn2 = *(const bf16x4*)(ppi + (size_t)xsA[2] * H_); });
        K2_STEP(1, xc3, { xn3 = *(const bf16x4*)(ppi + (size_t)xsA[3] * H_);
                          xsB = *(const i32x4*)(xnext); });

        xc0 = xn0; xc1 = xn1; xc2 = xn2; xc3 = xn3;
        xsA = xsB;
    }
#undef K2_STEP

    // final h of step T-1 -> hg granules for K3
    *(bf16x4*)&hg[(size_t)(bi >> 3) * 16384 + (size_t)(bi & 7) * 2048 + wb] = h4;
}

// ---------------------------------------------------------------------------
// K3: out[b][v] = h[b] @ W_fc[v]^T + b_fc[v]. grid (250, 4): 1000 blocks,
// each 128 v x 256 b (2 bt-tiles) -> ~4 blocks/CU so store drains overlap
// other blocks' loads. Nontemporal stores: out is pure streaming (never
// re-read) — keep L2 for Wfc/hg. A-frags cvt'd from f32 Wfc once per block.
// ---------------------------------------------------------------------------
__global__ __launch_bounds__(512, 1) void k3_head(
    const float* __restrict__ Wfc, const __bf16* __restrict__ hg,
    const float* __restrict__ bfc, float* __restrict__ out)
{
    const int tid = threadIdx.x;
    const int lane = tid & 63, w = tid >> 6;
    const int gv = blockIdx.x;
    const int v0 = gv * 128;
    const int bt0 = blockIdx.y * 2;
    const int sub = lane >> 4, rc = lane & 15;
    const int mt0 = (w & 3) * 2, nt0 = (w >> 2) * 4;

    bf16x8 af[2][4];
#pragma unroll
    for (int m = 0; m < 2; ++m)
#pragma unroll
        for (int kc = 0; kc < 4; ++kc) {
            int row = v0 + (mt0 + m) * 16 + rc;
            const float* src = Wfc + (size_t)row * H_ + (kc * 4 + sub) * 8;
            f32x4 p0 = *(const f32x4*)src, p1 = *(const f32x4*)(src + 4);
            bf16x8 h8;
#pragma unroll
            for (int e = 0; e < 4; ++e) {
                h8[e] = (__bf16)p0[e];
                h8[4 + e] = (__bf16)p1[e];
            }
            af[m][kc] = h8;
        }

    f32x4 bias4[2];
#pragma unroll
    for (int m = 0; m < 2; ++m)
        bias4[m] = *(const f32x4*)&bfc[v0 + (mt0 + m) * 16 + sub * 4];

#pragma unroll
    for (int bt = bt0; bt < bt0 + 2; ++bt) {
        const int b0 = bt * 128;
        f32x4 acc[2][4];
#pragma unroll
        for (int m = 0; m < 2; ++m)
#pragma unroll
            for (int n = 0; n < 4; ++n) acc[m][n] = (f32x4){0.f, 0.f, 0.f, 0.f};

#pragma unroll
        for (int kc = 0; kc < 4; ++kc) {
            bf16x8 bf[4];
#pragma unroll
            for (int n = 0; n < 4; ++n)
                bf[n] = *(const bf16x8*)&hg[(size_t)bt * 16384
                          + (size_t)(((nt0 + n) * 256) + kc * 64 + lane) * 8];
#pragma unroll
            for (int n = 0; n < 4; ++n)
#pragma unroll
                for (int m = 0; m < 2; ++m)
                    acc[m][n] = mfma16(af[m][kc], bf[n], acc[m][n]);
        }
#pragma unroll
        for (int n = 0; n < 4; ++n)
#pragma unroll
            for (int m = 0; m < 2; ++m) {
                f32x4 v = acc[m][n] + bias4[m];
                float* dst = out + (size_t)(b0 + (nt0 + n) * 16 + rc) * V_
                                 + v0 + (mt0 + m) * 16 + sub * 4;
                __builtin_nontemporal_store(v, (f32x4*)dst);
            }
    }
}

extern "C" void kernel_launch(void* const* d_in, const int* in_sizes, int n_in,
                              void* d_out, int out_size, void* d_ws, size_t ws_size,
                              hipStream_t stream) {
    const int*   x   = (const int*)d_in[0];
    const float* emb = (const float*)d_in[1];
    const float* Wih = (const float*)d_in[2];
    const float* Whh = (const float*)d_in[3];
    const float* bih = (const float*)d_in[4];
    const float* bhh = (const float*)d_in[5];
    const float* Wfc = (const float*)d_in[6];
    const float* bfc = (const float*)d_in[7];
    float* out = (float*)d_out;

    const size_t SZ_HG = 262144;                    // 8 x 16384 bf16
    const size_t SZ_PP = (size_t)V_ * H_ * 2;       // 8.192 MB

    char* wsb = (char*)d_ws;
    size_t off = 0;
    auto take = [&](size_t n) -> char* {
        char* p = wsb + off;
        off += (n + 255) & ~(size_t)255;
        return p;
    };
    auto fits = [&](size_t n) { return off + n + 256 <= ws_size; };

    __bf16* hgp = (__bf16*)take(SZ_HG);             // required in ws
    // pp: prefer ws; fallback into d_out (k3 overwrites it only after k2 done)
    __bf16* pp = fits(SZ_PP) ? (__bf16*)take(SZ_PP) : (__bf16*)d_out;

    k0_pp<<<dim3(500), 512, 0, stream>>>(emb, Wih, bih, bhh, pp);
    k2_rnn<<<dim3(64), 512, 0, stream>>>(x, pp, Whh, hgp);
    k3_head<<<dim3(250, 4), 512, 0, stream>>>(Wfc, hgp, bfc, out);
}

// Round 16
// 148.119 us; speedup vs baseline: 1.0968x; 1.0968x over previous
//
#include <hip/hip_runtime.h>
#include <hip/hip_bf16.h>

#define V_ 32000
#define E_ 100
#define H_ 128
#define B_ 1024
#define T_ 256

typedef float f32x4 __attribute__((ext_vector_type(4)));
typedef int   i32x4 __attribute__((ext_vector_type(4)));
typedef __bf16 bf16x8 __attribute__((ext_vector_type(8)));
typedef __bf16 bf16x4 __attribute__((ext_vector_type(4)));

__device__ __forceinline__ f32x4 mfma16(bf16x8 a, bf16x8 b, f32x4 c) {
    return __builtin_amdgcn_mfma_f32_16x16x32_bf16(a, b, c, 0, 0, 0);
}

// ---------------------------------------------------------------------------
// K0: pp[v][h] = bf16( emb[v,:] @ W_ih^T + b_ih + b_hh )  (K = 100, f32 acc)
// Input projection depends only on vocab id -> precompute once for all ids.
// grid 500 x 512thr; block covers 64 vocab; 8 waves = 4 v-tiles x 2 h-halves.
// ---------------------------------------------------------------------------
__global__ __launch_bounds__(512, 1) void k0_pp(
    const float* __restrict__ emb, const float* __restrict__ Wih,
    const float* __restrict__ bih, const float* __restrict__ bhh,
    __bf16* __restrict__ pp)
{
    const int tid = threadIdx.x;
    const int lane = tid & 63, w = tid >> 6;
    const int nt = w >> 1;               // vocab tile 0..3
    const int mh = w & 1;                // h half 0..1 (4 m-tiles each)
    const int v0 = blockIdx.x * 64;
    const int sub = lane >> 4, rc = lane & 15;
    const f32x4 z = {0.f, 0.f, 0.f, 0.f};

    bf16x8 af[4][4];
#pragma unroll
    for (int m = 0; m < 4; ++m)
#pragma unroll
        for (int kc = 0; kc < 4; ++kc) {
            int row = (mh * 4 + m) * 16 + rc;
            int k0 = kc * 32 + sub * 8;
            const float* s = Wih + (size_t)row * E_ + k0;
            f32x4 p0 = (k0 + 4 <= E_) ? *(const f32x4*)s : z;
            f32x4 p1 = (k0 + 8 <= E_) ? *(const f32x4*)(s + 4) : z;
            bf16x8 h8;
#pragma unroll
            for (int e = 0; e < 4; ++e) {
                h8[e] = (__bf16)p0[e];
                h8[4 + e] = (__bf16)p1[e];
            }
            af[m][kc] = h8;
        }

    bf16x8 bf[4];
#pragma unroll
    for (int kc = 0; kc < 4; ++kc) {
        int vrow = v0 + nt * 16 + rc;
        int k0 = kc * 32 + sub * 8;
        const float* s = emb + (size_t)vrow * E_ + k0;
        f32x4 p0 = (k0 + 4 <= E_) ? *(const f32x4*)s : z;
        f32x4 p1 = (k0 + 8 <= E_) ? *(const f32x4*)(s + 4) : z;
        bf16x8 h8;
#pragma unroll
        for (int e = 0; e < 4; ++e) {
            h8[e] = (__bf16)p0[e];
            h8[4 + e] = (__bf16)p1[e];
        }
        bf[kc] = h8;
    }

    f32x4 acc[4];
#pragma unroll
    for (int m = 0; m < 4; ++m) {
        int h0 = (mh * 4 + m) * 16 + sub * 4;
        acc[m] = *(const f32x4*)&bih[h0] + *(const f32x4*)&bhh[h0];
    }
#pragma unroll
    for (int kc = 0; kc < 4; ++kc)
#pragma unroll
        for (int m = 0; m < 4; ++m)
            acc[m] = mfma16(af[m][kc], bf[kc], acc[m]);

#pragma unroll
    for (int m = 0; m < 4; ++m) {
        int v = v0 + nt * 16 + rc;
        int h0 = (mh * 4 + m) * 16 + sub * 4;
        bf16x4 o;
#pragma unroll
        for (int r = 0; r < 4; ++r) o[r] = (__bf16)acc[m][r];
        *(bf16x4*)&pp[(size_t)v * H_ + h0] = o;
    }
}

// ---------------------------------------------------------------------------
// K2: RNN scan (R10 structure + 4 independent depth-1 MFMA accumulators).
// 64 blocks x 16 batch; 8 waves (2/SIMD); wave w owns hidden rows
// [16w,16w+16). xt from pp[x[b,t]] gathers, STAGGERED one-per-step (issued
// in step t for step t+4; sched_barrier(0) pins them per-step). Indices
// i32x4 loaded in step 3 of each group, pointer clamped at tail.
// Position-named regs (counted vmcnt). Static LDS ping-pong; xt folded into
// MFMA C-init; 1 barrier/step.
// ---------------------------------------------------------------------------
__global__ __launch_bounds__(512, 1) void k2_rnn(
    const int* __restrict__ x, const __bf16* __restrict__ pp,
    const float* __restrict__ Whh, __bf16* __restrict__ hg)
{
    __shared__ __align__(16) __bf16 Hg[2][2048];
    const int tid = threadIdx.x;
    const int lane = tid & 63, w = tid >> 6;
    const int bi = blockIdx.x;
    const int b0 = bi * 16;
    const int sub = lane >> 4, c = lane & 15;

    // A fragments: W_hh rows w*16 + c (bf16); loop-invariant
    bf16x8 wah[4];
#pragma unroll
    for (int kc = 0; kc < 4; ++kc) {
        const float* src = Whh + (size_t)(w * 16 + c) * H_ + kc * 32 + sub * 8;
        f32x4 p0 = *(const f32x4*)src, p1 = *(const f32x4*)(src + 4);
        bf16x8 h8;
#pragma unroll
        for (int e = 0; e < 4; ++e) {
            h8[e] = (__bf16)p0[e];
            h8[4 + e] = (__bf16)p1[e];
        }
        wah[kc] = h8;
    }

    if (tid < 256) {
        bf16x8 z8;
#pragma unroll
        for (int e = 0; e < 8; ++e) z8[e] = (__bf16)0.0f;
        *(bf16x8*)&Hg[0][tid * 8] = z8;
    }
    __syncthreads();

    const int i0 = w * 16 + sub * 4;            // this lane's 4 hidden-out rows
    const int* xrow = x + (size_t)(b0 + c) * T_; // this lane's batch index row
    const __bf16* ppi = pp + i0;

    // LDS write elem-offset for hidden rows i0..i0+3, col c (granule layout)
    const int wb = (((w >> 1) * 64 + ((w & 1) * 2 + (sub >> 1)) * 16 + c) << 3)
                 + (sub & 1) * 4;

    bf16x4 h4;                                   // last-written h (for hg)

    // GBODY: one gather / index-load, placed after MFMA issue within the step
#define K2_STEP(PK, XREG, GBODY) do {                                       \
        const __bf16* Hp = &Hg[PK][0];                                      \
        bf16x8 hb0 = *(const bf16x8*)(Hp + lane * 8);                       \
        bf16x8 hb1 = *(const bf16x8*)(Hp + 512 + lane * 8);                 \
        bf16x8 hb2 = *(const bf16x8*)(Hp + 1024 + lane * 8);                \
        bf16x8 hb3 = *(const bf16x8*)(Hp + 1536 + lane * 8);                \
        f32x4 xf;                                                           \
        _Pragma("unroll")                                                   \
        for (int r = 0; r < 4; ++r) xf[r] = (float)XREG[r];                 \
        f32x4 zz = {0.f, 0.f, 0.f, 0.f};                                    \
        f32x4 a0 = mfma16(wah[0], hb0, xf);                                 \
        f32x4 a1 = mfma16(wah[1], hb1, zz);                                 \
        f32x4 a2 = mfma16(wah[2], hb2, zz);                                 \
        f32x4 a3 = mfma16(wah[3], hb3, zz);                                 \
        GBODY;                                                              \
        f32x4 s = (a0 + a1) + (a2 + a3);                                    \
        _Pragma("unroll")                                                   \
        for (int r = 0; r < 4; ++r) {                                       \
            float e;                                                        \
            asm("v_exp_f32 %0, %1" : "=v"(e) : "v"(s[r] * 2.8853900817779268f)); \
            float ep1 = e + 1.0f;                                           \
            float rcp;                                                      \
            asm("v_rcp_f32 %0, %1" : "=v"(rcp) : "v"(ep1));                 \
            h4[r] = (__bf16)(1.0f - 2.0f * rcp);                            \
        }                                                                   \
        *(bf16x4*)&Hg[(PK) ^ 1][wb] = h4;                                   \
        asm volatile("s_waitcnt lgkmcnt(0)" ::: "memory");                  \
        __builtin_amdgcn_s_barrier();                                       \
        __builtin_amdgcn_sched_barrier(0);                                  \
    } while (0)

    // prologue: indices + gathers for steps 0..3; indices for steps 4..7
    i32x4 xs0 = *(const i32x4*)(xrow);
    bf16x4 xc0 = *(const bf16x4*)(ppi + (size_t)xs0[0] * H_);
    bf16x4 xc1 = *(const bf16x4*)(ppi + (size_t)xs0[1] * H_);
    bf16x4 xc2 = *(const bf16x4*)(ppi + (size_t)xs0[2] * H_);
    bf16x4 xc3 = *(const bf16x4*)(ppi + (size_t)xs0[3] * H_);
    i32x4 xsA = *(const i32x4*)(xrow + 4);

    for (int j = 0; j < T_ / 4; ++j) {
        bf16x4 xn0, xn1, xn2, xn3;
        i32x4 xsB;
        // clamped pointers: tail groups read valid (unused) data
        int tg = 4 * (j + 2);
        const int* xnext = xrow + (tg <= T_ - 4 ? tg : T_ - 4);

        K2_STEP(0, xc0, { xn0 = *(const bf16x4*)(ppi + (size_t)xsA[0] * H_); });
        K2_STEP(1, xc1, { xn1 = *(const bf16x4*)(ppi + (size_t)xsA[1] * H_); });
        K2_STEP(0, xc2, { xn2 = *(const bf16x4*)(ppi + (size_t)xsA[2] * H_); });
        K2_STEP(1, xc3, { xn3 = *(const bf16x4*)(ppi + (size_t)xsA[3] * H_);
                          xsB = *(const i32x4*)(xnext); });

        xc0 = xn0; xc1 = xn1; xc2 = xn2; xc3 = xn3;
        xsA = xsB;
    }
#undef K2_STEP

    // final h of step T-1 -> hg granules for K3
    *(bf16x4*)&hg[(size_t)(bi >> 3) * 16384 + (size_t)(bi & 7) * 2048 + wb] = h4;
}

// ---------------------------------------------------------------------------
// K3: out[b][v] = h[b] @ W_fc[v]^T + b_fc[v]. One block per v-tile (gv);
// A-frags cvt'd from f32 Wfc ONCE, loop over all 8 batch-tiles. grid 250.
// (R10-exact: grid(250,4)+nontemporal stores regressed 16 µs in R15 —
// 4x Wfc re-reads + worse write-combining. Regular stores, 1 block/v-tile.)
// ---------------------------------------------------------------------------
__global__ __launch_bounds__(512, 1) void k3_head(
    const float* __restrict__ Wfc, const __bf16* __restrict__ hg,
    const float* __restrict__ bfc, float* __restrict__ out)
{
    const int tid = threadIdx.x;
    const int lane = tid & 63, w = tid >> 6;
    const int gv = blockIdx.x;
    const int v0 = gv * 128;
    const int sub = lane >> 4, rc = lane & 15;
    const int mt0 = (w & 3) * 2, nt0 = (w >> 2) * 4;

    bf16x8 af[2][4];
#pragma unroll
    for (int m = 0; m < 2; ++m)
#pragma unroll
        for (int kc = 0; kc < 4; ++kc) {
            int row = v0 + (mt0 + m) * 16 + rc;
            const float* src = Wfc + (size_t)row * H_ + (kc * 4 + sub) * 8;
            f32x4 p0 = *(const f32x4*)src, p1 = *(const f32x4*)(src + 4);
            bf16x8 h8;
#pragma unroll
            for (int e = 0; e < 4; ++e) {
                h8[e] = (__bf16)p0[e];
                h8[4 + e] = (__bf16)p1[e];
            }
            af[m][kc] = h8;
        }

    f32x4 bias4[2];
#pragma unroll
    for (int m = 0; m < 2; ++m)
        bias4[m] = *(const f32x4*)&bfc[v0 + (mt0 + m) * 16 + sub * 4];

    for (int bt = 0; bt < 8; ++bt) {
        const int b0 = bt * 128;
        f32x4 acc[2][4];
#pragma unroll
        for (int m = 0; m < 2; ++m)
#pragma unroll
            for (int n = 0; n < 4; ++n) acc[m][n] = (f32x4){0.f, 0.f, 0.f, 0.f};

#pragma unroll
        for (int kc = 0; kc < 4; ++kc) {
            bf16x8 bf[4];
#pragma unroll
            for (int n = 0; n < 4; ++n)
                bf[n] = *(const bf16x8*)&hg[(size_t)bt * 16384
                          + (size_t)(((nt0 + n) * 256) + kc * 64 + lane) * 8];
#pragma unroll
            for (int n = 0; n < 4; ++n)
#pragma unroll
                for (int m = 0; m < 2; ++m)
                    acc[m][n] = mfma16(af[m][kc], bf[n], acc[m][n]);
        }
#pragma unroll
        for (int n = 0; n < 4; ++n)
#pragma unroll
            for (int m = 0; m < 2; ++m) {
                f32x4 v = acc[m][n] + bias4[m];
                float* dst = out + (size_t)(b0 + (nt0 + n) * 16 + rc) * V_
                                 + v0 + (mt0 + m) * 16 + sub * 4;
                *(f32x4*)dst = v;
            }
    }
}

extern "C" void kernel_launch(void* const* d_in, const int* in_sizes, int n_in,
                              void* d_out, int out_size, void* d_ws, size_t ws_size,
                              hipStream_t stream) {
    const int*   x   = (const int*)d_in[0];
    const float* emb = (const float*)d_in[1];
    const float* Wih = (const float*)d_in[2];
    const float* Whh = (const float*)d_in[3];
    const float* bih = (const float*)d_in[4];
    const float* bhh = (const float*)d_in[5];
    const float* Wfc = (const float*)d_in[6];
    const float* bfc = (const float*)d_in[7];
    float* out = (float*)d_out;

    const size_t SZ_HG = 262144;                    // 8 x 16384 bf16
    const size_t SZ_PP = (size_t)V_ * H_ * 2;       // 8.192 MB

    char* wsb = (char*)d_ws;
    size_t off = 0;
    auto take = [&](size_t n) -> char* {
        char* p = wsb + off;
        off += (n + 255) & ~(size_t)255;
        return p;
    };
    auto fits = [&](size_t n) { return off + n + 256 <= ws_size; };

    __bf16* hgp = (__bf16*)take(SZ_HG);             // required in ws
    // pp: prefer ws; fallback into d_out (k3 overwrites it only after k2 done)
    __bf16* pp = fits(SZ_PP) ? (__bf16*)take(SZ_PP) : (__bf16*)d_out;

    k0_pp<<<dim3(500), 512, 0, stream>>>(emb, Wih, bih, bhh, pp);
    k2_rnn<<<dim3(64), 512, 0, stream>>>(x, pp, Whh, hgp);
    k3_head<<<dim3(250), 512, 0, stream>>>(Wfc, hgp, bfc, out);
}

// Round 17
// 146.199 us; speedup vs baseline: 1.1112x; 1.0131x over previous
//
#include <hip/hip_runtime.h>
#include <hip/hip_bf16.h>

#define V_ 32000
#define E_ 100
#define H_ 128
#define B_ 1024
#define T_ 256

typedef float f32x4 __attribute__((ext_vector_type(4)));
typedef int   i32x4 __attribute__((ext_vector_type(4)));
typedef __bf16 bf16x8 __attribute__((ext_vector_type(8)));
typedef __bf16 bf16x4 __attribute__((ext_vector_type(4)));

__device__ __forceinline__ f32x4 mfma16(bf16x8 a, bf16x8 b, f32x4 c) {
    return __builtin_amdgcn_mfma_f32_16x16x32_bf16(a, b, c, 0, 0, 0);
}

// ---------------------------------------------------------------------------
// K0: pp[v][h] = bf16( emb[v,:] @ W_ih^T + b_ih + b_hh )  (K = 100, f32 acc)
// Input projection depends only on vocab id -> precompute once for all ids.
// grid 500 x 512thr; block covers 64 vocab; 8 waves = 4 v-tiles x 2 h-halves.
// ---------------------------------------------------------------------------
__global__ __launch_bounds__(512, 1) void k0_pp(
    const float* __restrict__ emb, const float* __restrict__ Wih,
    const float* __restrict__ bih, const float* __restrict__ bhh,
    __bf16* __restrict__ pp)
{
    const int tid = threadIdx.x;
    const int lane = tid & 63, w = tid >> 6;
    const int nt = w >> 1;               // vocab tile 0..3
    const int mh = w & 1;                // h half 0..1 (4 m-tiles each)
    const int v0 = blockIdx.x * 64;
    const int sub = lane >> 4, rc = lane & 15;
    const f32x4 z = {0.f, 0.f, 0.f, 0.f};

    bf16x8 af[4][4];
#pragma unroll
    for (int m = 0; m < 4; ++m)
#pragma unroll
        for (int kc = 0; kc < 4; ++kc) {
            int row = (mh * 4 + m) * 16 + rc;
            int k0 = kc * 32 + sub * 8;
            const float* s = Wih + (size_t)row * E_ + k0;
            f32x4 p0 = (k0 + 4 <= E_) ? *(const f32x4*)s : z;
            f32x4 p1 = (k0 + 8 <= E_) ? *(const f32x4*)(s + 4) : z;
            bf16x8 h8;
#pragma unroll
            for (int e = 0; e < 4; ++e) {
                h8[e] = (__bf16)p0[e];
                h8[4 + e] = (__bf16)p1[e];
            }
            af[m][kc] = h8;
        }

    bf16x8 bf[4];
#pragma unroll
    for (int kc = 0; kc < 4; ++kc) {
        int vrow = v0 + nt * 16 + rc;
        int k0 = kc * 32 + sub * 8;
        const float* s = emb + (size_t)vrow * E_ + k0;
        f32x4 p0 = (k0 + 4 <= E_) ? *(const f32x4*)s : z;
        f32x4 p1 = (k0 + 8 <= E_) ? *(const f32x4*)(s + 4) : z;
        bf16x8 h8;
#pragma unroll
        for (int e = 0; e < 4; ++e) {
            h8[e] = (__bf16)p0[e];
            h8[4 + e] = (__bf16)p1[e];
        }
        bf[kc] = h8;
    }

    f32x4 acc[4];
#pragma unroll
    for (int m = 0; m < 4; ++m) {
        int h0 = (mh * 4 + m) * 16 + sub * 4;
        acc[m] = *(const f32x4*)&bih[h0] + *(const f32x4*)&bhh[h0];
    }
#pragma unroll
    for (int kc = 0; kc < 4; ++kc)
#pragma unroll
        for (int m = 0; m < 4; ++m)
            acc[m] = mfma16(af[m][kc], bf[kc], acc[m]);

#pragma unroll
    for (int m = 0; m < 4; ++m) {
        int v = v0 + nt * 16 + rc;
        int h0 = (mh * 4 + m) * 16 + sub * 4;
        bf16x4 o;
#pragma unroll
        for (int r = 0; r < 4; ++r) o[r] = (__bf16)acc[m][r];
        *(bf16x4*)&pp[(size_t)v * H_ + h0] = o;
    }
}

// ---------------------------------------------------------------------------
// K2: RNN scan (R10-exact — measured best, 94.7 µs). 64 blocks x 16 batch;
// 8 waves (2/SIMD); wave w owns hidden rows [16w,16w+16). xt from
// pp[x[b,t]] gathers, STAGGERED one-per-step (issued in step t for step
// t+4; sched_barrier(0) pins them per-step). Indices i32x4 loaded in step 3
// of each group, pointer clamped at tail. Position-named regs (counted
// vmcnt). Static LDS ping-pong; xt folded into MFMA C-init; 2 MFMA chains
// of depth 2 (depth-1 x4 + extra adds measured slower, R16); 1 barrier/step.
// ---------------------------------------------------------------------------
__global__ __launch_bounds__(512, 1) void k2_rnn(
    const int* __restrict__ x, const __bf16* __restrict__ pp,
    const float* __restrict__ Whh, __bf16* __restrict__ hg)
{
    __shared__ __align__(16) __bf16 Hg[2][2048];
    const int tid = threadIdx.x;
    const int lane = tid & 63, w = tid >> 6;
    const int bi = blockIdx.x;
    const int b0 = bi * 16;
    const int sub = lane >> 4, c = lane & 15;

    // A fragments: W_hh rows w*16 + c (bf16); loop-invariant
    bf16x8 wah[4];
#pragma unroll
    for (int kc = 0; kc < 4; ++kc) {
        const float* src = Whh + (size_t)(w * 16 + c) * H_ + kc * 32 + sub * 8;
        f32x4 p0 = *(const f32x4*)src, p1 = *(const f32x4*)(src + 4);
        bf16x8 h8;
#pragma unroll
        for (int e = 0; e < 4; ++e) {
            h8[e] = (__bf16)p0[e];
            h8[4 + e] = (__bf16)p1[e];
        }
        wah[kc] = h8;
    }

    if (tid < 256) {
        bf16x8 z8;
#pragma unroll
        for (int e = 0; e < 8; ++e) z8[e] = (__bf16)0.0f;
        *(bf16x8*)&Hg[0][tid * 8] = z8;
    }
    __syncthreads();

    const int i0 = w * 16 + sub * 4;            // this lane's 4 hidden-out rows
    const int* xrow = x + (size_t)(b0 + c) * T_; // this lane's batch index row
    const __bf16* ppi = pp + i0;

    // LDS write elem-offset for hidden rows i0..i0+3, col c (granule layout)
    const int wb = (((w >> 1) * 64 + ((w & 1) * 2 + (sub >> 1)) * 16 + c) << 3)
                 + (sub & 1) * 4;

    bf16x4 h4;                                   // last-written h (for hg)

    // GBODY: one gather / index-load, placed after MFMA issue within the step
#define K2_STEP(PK, XREG, GBODY) do {                                       \
        const __bf16* Hp = &Hg[PK][0];                                      \
        bf16x8 hb0 = *(const bf16x8*)(Hp + lane * 8);                       \
        bf16x8 hb1 = *(const bf16x8*)(Hp + 512 + lane * 8);                 \
        bf16x8 hb2 = *(const bf16x8*)(Hp + 1024 + lane * 8);                \
        bf16x8 hb3 = *(const bf16x8*)(Hp + 1536 + lane * 8);                \
        f32x4 xf;                                                           \
        _Pragma("unroll")                                                   \
        for (int r = 0; r < 4; ++r) xf[r] = (float)XREG[r];                 \
        f32x4 zz = {0.f, 0.f, 0.f, 0.f};                                    \
        f32x4 a0 = mfma16(wah[0], hb0, xf);                                 \
        f32x4 a1 = mfma16(wah[1], hb1, zz);                                 \
        a0 = mfma16(wah[2], hb2, a0);                                       \
        a1 = mfma16(wah[3], hb3, a1);                                       \
        GBODY;                                                              \
        f32x4 s = a0 + a1;                                                  \
        _Pragma("unroll")                                                   \
        for (int r = 0; r < 4; ++r) {                                       \
            float e;                                                        \
            asm("v_exp_f32 %0, %1" : "=v"(e) : "v"(s[r] * 2.8853900817779268f)); \
            float ep1 = e + 1.0f;                                           \
            float rcp;                                                      \
            asm("v_rcp_f32 %0, %1" : "=v"(rcp) : "v"(ep1));                 \
            h4[r] = (__bf16)(1.0f - 2.0f * rcp);                            \
        }                                                                   \
        *(bf16x4*)&Hg[(PK) ^ 1][wb] = h4;                                   \
        asm volatile("s_waitcnt lgkmcnt(0)" ::: "memory");                  \
        __builtin_amdgcn_s_barrier();                                       \
        __builtin_amdgcn_sched_barrier(0);                                  \
    } while (0)

    // prologue: indices + gathers for steps 0..3; indices for steps 4..7
    i32x4 xs0 = *(const i32x4*)(xrow);
    bf16x4 xc0 = *(const bf16x4*)(ppi + (size_t)xs0[0] * H_);
    bf16x4 xc1 = *(const bf16x4*)(ppi + (size_t)xs0[1] * H_);
    bf16x4 xc2 = *(const bf16x4*)(ppi + (size_t)xs0[2] * H_);
    bf16x4 xc3 = *(const bf16x4*)(ppi + (size_t)xs0[3] * H_);
    i32x4 xsA = *(const i32x4*)(xrow + 4);

    for (int j = 0; j < T_ / 4; ++j) {
        bf16x4 xn0, xn1, xn2, xn3;
        i32x4 xsB;
        // clamped pointers: tail groups read valid (unused) data
        int tg = 4 * (j + 2);
        const int* xnext = xrow + (tg <= T_ - 4 ? tg : T_ - 4);

        K2_STEP(0, xc0, { xn0 = *(const bf16x4*)(ppi + (size_t)xsA[0] * H_); });
        K2_STEP(1, xc1, { xn1 = *(const bf16x4*)(ppi + (size_t)xsA[1] * H_); });
        K2_STEP(0, xc2, { xn2 = *(const bf16x4*)(ppi + (size_t)xsA[2] * H_); });
        K2_STEP(1, xc3, { xn3 = *(const bf16x4*)(ppi + (size_t)xsA[3] * H_);
                          xsB = *(const i32x4*)(xnext); });

        xc0 = xn0; xc1 = xn1; xc2 = xn2; xc3 = xn3;
        xsA = xsB;
    }
#undef K2_STEP

    // final h of step T-1 -> hg granules for K3
    *(bf16x4*)&hg[(size_t)(bi >> 3) * 16384 + (size_t)(bi & 7) * 2048 + wb] = h4;
}

// ---------------------------------------------------------------------------
// K3: out[b][v] = h[b] @ W_fc[v]^T + b_fc[v]. One block per v-tile (gv);
// A-frags cvt'd from f32 Wfc ONCE, loop over all 8 batch-tiles. grid 250.
// (R10-exact: grid(250,4)+nontemporal stores regressed 16 µs in R15.)
// ---------------------------------------------------------------------------
__global__ __launch_bounds__(512, 1) void k3_head(
    const float* __restrict__ Wfc, const __bf16* __restrict__ hg,
    const float* __restrict__ bfc, float* __restrict__ out)
{
    const int tid = threadIdx.x;
    const int lane = tid & 63, w = tid >> 6;
    const int gv = blockIdx.x;
    const int v0 = gv * 128;
    const int sub = lane >> 4, rc = lane & 15;
    const int mt0 = (w & 3) * 2, nt0 = (w >> 2) * 4;

    bf16x8 af[2][4];
#pragma unroll
    for (int m = 0; m < 2; ++m)
#pragma unroll
        for (int kc = 0; kc < 4; ++kc) {
            int row = v0 + (mt0 + m) * 16 + rc;
            const float* src = Wfc + (size_t)row * H_ + (kc * 4 + sub) * 8;
            f32x4 p0 = *(const f32x4*)src, p1 = *(const f32x4*)(src + 4);
            bf16x8 h8;
#pragma unroll
            for (int e = 0; e < 4; ++e) {
                h8[e] = (__bf16)p0[e];
                h8[4 + e] = (__bf16)p1[e];
            }
            af[m][kc] = h8;
        }

    f32x4 bias4[2];
#pragma unroll
    for (int m = 0; m < 2; ++m)
        bias4[m] = *(const f32x4*)&bfc[v0 + (mt0 + m) * 16 + sub * 4];

    for (int bt = 0; bt < 8; ++bt) {
        const int b0 = bt * 128;
        f32x4 acc[2][4];
#pragma unroll
        for (int m = 0; m < 2; ++m)
#pragma unroll
            for (int n = 0; n < 4; ++n) acc[m][n] = (f32x4){0.f, 0.f, 0.f, 0.f};

#pragma unroll
        for (int kc = 0; kc < 4; ++kc) {
            bf16x8 bf[4];
#pragma unroll
            for (int n = 0; n < 4; ++n)
                bf[n] = *(const bf16x8*)&hg[(size_t)bt * 16384
                          + (size_t)(((nt0 + n) * 256) + kc * 64 + lane) * 8];
#pragma unroll
            for (int n = 0; n < 4; ++n)
#pragma unroll
                for (int m = 0; m < 2; ++m)
                    acc[m][n] = mfma16(af[m][kc], bf[n], acc[m][n]);
        }
#pragma unroll
        for (int n = 0; n < 4; ++n)
#pragma unroll
            for (int m = 0; m < 2; ++m) {
                f32x4 v = acc[m][n] + bias4[m];
                float* dst = out + (size_t)(b0 + (nt0 + n) * 16 + rc) * V_
                                 + v0 + (mt0 + m) * 16 + sub * 4;
                *(f32x4*)dst = v;
            }
    }
}

extern "C" void kernel_launch(void* const* d_in, const int* in_sizes, int n_in,
                              void* d_out, int out_size, void* d_ws, size_t ws_size,
                              hipStream_t stream) {
    const int*   x   = (const int*)d_in[0];
    const float* emb = (const float*)d_in[1];
    const float* Wih = (const float*)d_in[2];
    const float* Whh = (const float*)d_in[3];
    const float* bih = (const float*)d_in[4];
    const float* bhh = (const float*)d_in[5];
    const float* Wfc = (const float*)d_in[6];
    const float* bfc = (const float*)d_in[7];
    float* out = (float*)d_out;

    const size_t SZ_HG = 262144;                    // 8 x 16384 bf16
    const size_t SZ_PP = (size_t)V_ * H_ * 2;       // 8.192 MB

    char* wsb = (char*)d_ws;
    size_t off = 0;
    auto take = [&](size_t n) -> char* {
        char* p = wsb + off;
        off += (n + 255) & ~(size_t)255;
        return p;
    };
    auto fits = [&](size_t n) { return off + n + 256 <= ws_size; };

    __bf16* hgp = (__bf16*)take(SZ_HG);             // required in ws
    // pp: prefer ws; fallback into d_out (k3 overwrites it only after k2 done)
    __bf16* pp = fits(SZ_PP) ? (__bf16*)take(SZ_PP) : (__bf16*)d_out;

    k0_pp<<<dim3(500), 512, 0, stream>>>(emb, Wih, bih, bhh, pp);
    k2_rnn<<<dim3(64), 512, 0, stream>>>(x, pp, Whh, hgp);
    k3_head<<<dim3(250), 512, 0, stream>>>(Wfc, hgp, bfc, out);
}